// Round 12
// baseline (224.499 us; speedup 1.0000x reference)
//
#include <hip/hip_runtime.h>
#include <math.h>

// Problem constants
#define BB   16
#define CC   64
#define DIN  192     // C*K
#define DOUT 128
#define NEXP 8
#define NMAT 9       // 8 routed + 1 shared
#define NTOK 65536   // B*H*W
#define CAP  65568   // per-expert bucket capacity
#define SLABROWS 65552  // NTOK + 16 (dump rows for padding)

#define TOKSTRIDE 200   // LDS bf16 token row stride
#define QSTRIDE 56      // LDS bf16 stride for 48-f quarter rows (112 B, 16B mult)
#define LOGSTRIDE 9
#define CSTRIDE 136     // k4 LDS C-tile stride (shorts)

typedef short bf16x8 __attribute__((ext_vector_type(8)));
typedef float f32x4  __attribute__((ext_vector_type(4)));

// ---- workspace layout (bytes) ----
#define WS_TOK   0u          // bf16[NTOK][192]            25165824
#define WS_WT    25165824u   // bf16[9][128][192]          442368
#define WS_CNT   25608192u   // int[16]                    64
#define WS_RT    25608256u   // int[8][CAP] token|slot<<20 2098176
#define WS_RG    27706432u   // float[8][CAP]              2098176
#define WS_SLAB  29804608u   // bf16[2][SLABROWS][128]     33562624
#define WS_TOTAL 63367232u
// lpart (fp32[4][NTOK][8] = 8 MB) aliases the START of WS_SLAB: written by
// k1a, read by k1b, then fully overwritten by k4 before k3 reads slab.
#define LPQ 524288           // floats per channel-quarter

__device__ __forceinline__ unsigned short f2bf(float f) {
    union { float f; unsigned u; } v; v.f = f;
    unsigned u = v.u;
    u += 0x7fffu + ((u >> 16) & 1u);   // RNE (inputs finite)
    return (unsigned short)(u >> 16);
}
__device__ __forceinline__ float bf2f(unsigned short s) {
    union { unsigned u; float f; } v; v.u = ((unsigned)s) << 16;
    return v.f;
}

// ---------------- K1a: conv (channel-QUARTER) + router partials ---------------
// grid 4096 = (b,h) x qtr; 16 channels/block as 2 pipelined 8-ch chunks.
// x staged via coalesced float4 (one vmcnt wait/chunk); chunk-1 loads issued
// before chunk-0 compute (register bounce).
__global__ __launch_bounds__(256)
void k1a_conv(const float* __restrict__ x,
              const float* __restrict__ conv_w,
              const float* __restrict__ router_w,
              unsigned short* __restrict__ tokbuf,
              float* __restrict__ lpart,
              int* __restrict__ cnt)
{
    __shared__ __attribute__((aligned(16))) float xs[2][8 * 192];   // 12.3 KB
    __shared__ __attribute__((aligned(16))) unsigned short tokbf[64 * QSTRIDE]; // 7.2 KB
    __shared__ float logits[64 * LOGSTRIDE];

    const int tid = threadIdx.x;
    const int bid = blockIdx.x;
    const int bh  = bid >> 2;
    const int qtr = bid & 3;
    const int b   = bh >> 6;
    const int h   = bh & 63;
    const int cbase = qtr * 16;

    if (bid == 0 && tid < 16) cnt[tid] = 0;
    for (int idx = tid; idx < 64 * LOGSTRIDE; idx += 256) logits[idx] = 0.f;

    const int   h0  = (h > 0)  ? (h - 1) : 0;
    const int   h2  = (h < 63) ? (h + 1) : 63;
    const float mh0 = (h > 0)  ? 1.f : 0.f;
    const float mh2 = (h < 63) ? 1.f : 0.f;

    // staging map: 384 float4 per 8-ch chunk: c=idx/48, row=(idx%48)/16, seg=idx%16
    int sc[2], srow[2], sseg[2]; bool sv[2];
    #pragma unroll
    for (int q = 0; q < 2; ++q) {
        int idx = q * 256 + tid;
        sv[q] = idx < 384;
        sc[q] = idx / 48;
        int rem = idx % 48;
        srow[q] = rem >> 4; sseg[q] = rem & 15;
    }
    const float* xb = x + (size_t)b * CC * 4096;

    // ---- stage chunk 0 (channels cbase..cbase+7) ----
    #pragma unroll
    for (int q = 0; q < 2; ++q) if (sv[q]) {
        int hh = (srow[q] == 0) ? h0 : ((srow[q] == 1) ? h : h2);
        float4 v = *(const float4*)(xb + ((size_t)(cbase + sc[q]) * 64 + hh) * 64
                                       + sseg[q] * 4);
        *(float4*)&xs[0][sc[q] * 192 + srow[q] * 64 + sseg[q] * 4] = v;
    }
    __syncthreads();

    const int w  = tid & 63;
    const int cq = __builtin_amdgcn_readfirstlane(tid >> 6); // wave-uniform

    const int   wm  = (w == 0)  ? 0  : (w - 1);
    const int   wp  = (w == 63) ? 63 : (w + 1);
    const float mwm = (w == 0)  ? 0.f : 1.f;
    const float mwp = (w == 63) ? 0.f : 1.f;

    float lacc[8];
    #pragma unroll
    for (int e = 0; e < 8; ++e) lacc[e] = 0.f;

    // ---- issue chunk-1 loads (vmcnt wait lands after chunk-0 compute) ----
    float4 st1[2];
    #pragma unroll
    for (int q = 0; q < 2; ++q) if (sv[q]) {
        int hh = (srow[q] == 0) ? h0 : ((srow[q] == 1) ? h : h2);
        st1[q] = *(const float4*)(xb + ((size_t)(cbase + 8 + sc[q]) * 64 + hh) * 64
                                     + sseg[q] * 4);
    }

    // ---- compute both chunks ----
    #pragma unroll
    for (int ch = 0; ch < 2; ++ch) {
        const float* xsc = xs[ch];
        #pragma unroll
        for (int i = 0; i < 2; ++i) {
            int cc = cq * 2 + i;                       // channel within chunk
            int cl = ch * 8 + cc;                      // channel within quarter
            int c  = cbase + cl;                       // global channel
            const float* r0 = xsc + cc * 192;
            const float* r1 = r0 + 64;
            const float* r2 = r0 + 128;
            float x00 = r0[wm], x01 = r0[w], x02 = r0[wp];
            float x10 = r1[wm], x11 = r1[w], x12 = r1[wp];
            float x20 = r2[wm], x21 = r2[w], x22 = r2[wp];
            x00 *= mh0 * mwm; x01 *= mh0; x02 *= mh0 * mwp;
            x10 *= mwm;                    x12 *= mwp;
            x20 *= mh2 * mwm; x21 *= mh2; x22 *= mh2 * mwp;

            #pragma unroll
            for (int j = 0; j < 3; ++j) {
                int fl = 3 * cl + j;                   // local f (0..47)
                int f  = 3 * c + j;                    // global f, wave-uniform
                const float* w9 = conv_w + f * 9;      // scalar loads (L2-hot)
                float acc = x00 * w9[0] + x01 * w9[1] + x02 * w9[2]
                          + x10 * w9[3] + x11 * w9[4] + x12 * w9[5]
                          + x20 * w9[6] + x21 * w9[7] + x22 * w9[8];
                tokbf[w * QSTRIDE + fl] = f2bf(acc);
                const float* rwf = router_w + f * 8;   // scalar loads
                #pragma unroll
                for (int e = 0; e < 8; ++e) lacc[e] += acc * rwf[e];
            }
        }
        if (ch == 0) {
            #pragma unroll
            for (int q = 0; q < 2; ++q) if (sv[q])
                *(float4*)&xs[1][sc[q] * 192 + srow[q] * 64 + sseg[q] * 4] = st1[q];
            __syncthreads();
        }
    }

    #pragma unroll
    for (int e = 0; e < 8; ++e)
        atomicAdd(&logits[w * LOGSTRIDE + e], lacc[e]);  // 4 threads/(w,e)
    __syncthreads();

    // partial logits -> global (coalesced)
    for (int idx = tid; idx < 512; idx += 256) {
        int wtok = idx >> 3, e = idx & 7;
        lpart[(size_t)qtr * LPQ + ((size_t)bh * 64 + wtok) * 8 + e] =
            logits[wtok * LOGSTRIDE + e];
    }
    // tokens LDS -> global (64 rows x 6 bf16x8 chunks)
    for (int idx = tid; idx < 384; idx += 256) {
        int row = idx / 6, seg = idx - row * 6;
        *(bf16x8*)(tokbuf + (size_t)(bh * 64 + row) * 192 + qtr * 48 + seg * 8) =
            *(const bf16x8*)(tokbf + row * QSTRIDE + seg * 8);
    }
}

// ---------------- K1b: sum 4 quarters, top-2, rank append + wt prep -----------
__global__ __launch_bounds__(256)
void k1b_route(const float* __restrict__ lpart,
               int* __restrict__ cnt,
               int* __restrict__ rowtok, float* __restrict__ rowgate,
               const float* __restrict__ w_experts,
               const float* __restrict__ w_shared,
               unsigned short* __restrict__ wt)
{
    __shared__ int lcnt[8];
    __shared__ int lbase[8];

    const int tid = threadIdx.x;
    const int blk = blockIdx.x;
    const int t   = blk * 256 + tid;          // 256 blocks x 256 tokens

    if (tid < 8) lcnt[tid] = 0;
    __syncthreads();

    float l[8];
    #pragma unroll
    for (int e = 0; e < 8; ++e) l[e] = 0.f;
    #pragma unroll
    for (int q = 0; q < 4; ++q) {
        const float* p = lpart + (size_t)q * LPQ + (size_t)t * 8;
        #pragma unroll
        for (int e = 0; e < 8; ++e) l[e] += p[e];
    }

    // fp32 exact top-2; strict > keeps lowest index on ties (lax.top_k)
    int e0 = 0; float l0 = l[0];
    #pragma unroll
    for (int e = 1; e < 8; ++e) if (l[e] > l0) { l0 = l[e]; e0 = e; }
    int e1 = -1; float l1 = -INFINITY;
    #pragma unroll
    for (int e = 0; e < 8; ++e) {
        if (e == e0) continue;
        if (l[e] > l1) { l1 = l[e]; e1 = e; }
    }
    float g0 = 1.f / (1.f + expf(l1 - l0));   // softmax Z cancels in renorm
    float g1 = 1.f - g0;

    // local ranks (LDS atomics), one global reservation per expert
    int r0 = atomicAdd(&lcnt[e0], 1);
    int r1 = atomicAdd(&lcnt[e1], 1);
    __syncthreads();
    if (tid < 8) lbase[tid] = atomicAdd(&cnt[tid], lcnt[tid]);
    __syncthreads();

    int p0i = e0 * CAP + lbase[e0] + r0;
    int p1i = e1 * CAP + lbase[e1] + r1;
    rowtok[p0i]  = t;
    rowgate[p0i] = g0;
    rowtok[p1i]  = t | (1 << 20);
    rowgate[p1i] = g1;

    // weight transpose slice: 864 elems/block of wt[e][n][k] = src[e][k][n]
    {
        int base = blk * 864;
        for (int q = 0; q < 4; ++q) {
            int idx = base + q * 256 + tid;
            if (idx < 221184 && (q * 256 + tid) < 864) {
                int e = idx / 24576, rem = idx - e * 24576;
                int n = rem / DIN,  k  = rem - n * DIN;
                const float* src = (e < 8) ? (w_experts + (size_t)e * DIN * DOUT)
                                           : w_shared;
                wt[idx] = f2bf(src[k * DOUT + n]);
            }
        }
    }
}

// ---------------- K4: routed GEMM, register-bounced A pipeline ----------------
// grid 4096 = 8 experts x 512 jb (~2 tiles/block). Next tile's rows loaded
// into REGISTERS before this tile's MFMA, then ds_written. Wide 16B stores.
__global__ __launch_bounds__(256)
void k4_routed(const unsigned short* __restrict__ tokbuf,
               const unsigned short* __restrict__ wt,
               const float* __restrict__ b_experts,
               const int* __restrict__ cnt,
               const int* __restrict__ rowtok, const float* __restrict__ rowgate,
               unsigned short* __restrict__ slab)
{
    __shared__ __attribute__((aligned(16))) unsigned short atile[2][16 * TOKSTRIDE];
    __shared__ __attribute__((aligned(16))) unsigned short ctile[2][16 * CSTRIDE];
    __shared__ int   stok[2][16];
    __shared__ float sgate[2][16];

    const int tid  = threadIdx.x;
    const int e    = blockIdx.x >> 9;         // 0..7
    const int jb   = blockIdx.x & 511;
    const int wave = tid >> 6;
    const int lane = tid & 63;
    const int m16  = lane & 15, quad = lane >> 4;
    const int o0   = (wave * 2 + 0) * 16 + m16;
    const int o1   = (wave * 2 + 1) * 16 + m16;

    const unsigned short* wb = wt + (size_t)e * DOUT * DIN;
    bf16x8 bfr0[6], bfr1[6];
    #pragma unroll
    for (int ks = 0; ks < 6; ++ks) {
        bfr0[ks] = *(const bf16x8*)(wb + (size_t)o0 * DIN + ks * 32 + quad * 8);
        bfr1[ks] = *(const bf16x8*)(wb + (size_t)o1 * DIN + ks * 32 + quad * 8);
    }
    const float be0 = b_experts[e * DOUT + o0];
    const float be1 = b_experts[e * DOUT + o1];

    const int cnt_e  = cnt[e];
    const int ntiles = (cnt_e + 15) >> 4;
    const int*   rt = rowtok  + e * CAP;
    const float* rg = rowgate + e * CAP;

    // staging map: idx = tid (+256): row=idx/24, seg=idx%24
    const int r0i = tid / 24,         s0i = tid - r0i * 24;
    const int r1i = (tid + 256) / 24, s1i = (tid + 256) - r1i * 24;
    const bool has1 = (tid + 256) < 384;

    // prologue: stage tile jb into buf 0
    if (jb < ntiles) {
        int base = jb * 16;
        if (tid < 16) {
            int r = base + tid;
            bool ok = (r < cnt_e);
            stok[0][tid]  = ok ? rt[r] : NTOK;
            sgate[0][tid] = ok ? rg[r] : 0.f;
        }
        {
            int ra = base + r0i;
            int raw = (ra < cnt_e) ? rt[ra] : NTOK;
            *(bf16x8*)&atile[0][r0i * TOKSTRIDE + s0i * 8] =
                *(const bf16x8*)(tokbuf + (size_t)(raw & 0x1FFFF) * 192 + s0i * 8);
            if (has1) {
                int rb = base + r1i;
                int rawb = (rb < cnt_e) ? rt[rb] : NTOK;
                *(bf16x8*)&atile[0][r1i * TOKSTRIDE + s1i * 8] =
                    *(const bf16x8*)(tokbuf + (size_t)(rawb & 0x1FFFF) * 192 + s1i * 8);
            }
        }
    }
    __syncthreads();

    int buf = 0;
    for (int j = jb; j < ntiles; j += 512, buf ^= 1) {
        const int jn = j + 512;
        const bool more = (jn < ntiles);

        // issue next tile's global loads into registers (no use yet)
        bf16x8 nx0 = {0,0,0,0,0,0,0,0}, nx1 = {0,0,0,0,0,0,0,0};
        int nmt = NTOK; float nmg = 0.f;
        if (more) {
            int base = jn * 16;
            if (tid < 16) {
                int r = base + tid;
                bool ok = (r < cnt_e);
                nmt = ok ? rt[r] : NTOK;
                nmg = ok ? rg[r] : 0.f;
            }
            int ra = base + r0i;
            int rawa = (ra < cnt_e) ? rt[ra] : NTOK;
            nx0 = *(const bf16x8*)(tokbuf + (size_t)(rawa & 0x1FFFF) * 192 + s0i * 8);
            if (has1) {
                int rb = base + r1i;
                int rawb = (rb < cnt_e) ? rt[rb] : NTOK;
                nx1 = *(const bf16x8*)(tokbuf + (size_t)(rawb & 0x1FFFF) * 192 + s1i * 8);
            }
        }

        // compute current tile
        bf16x8 a[6];
        #pragma unroll
        for (int ks = 0; ks < 6; ++ks)
            a[ks] = *(const bf16x8*)&atile[buf][m16 * TOKSTRIDE + ks * 32 + quad * 8];

        f32x4 acc0 = {0.f, 0.f, 0.f, 0.f};
        f32x4 acc1 = {0.f, 0.f, 0.f, 0.f};
        #pragma unroll
        for (int ks = 0; ks < 6; ++ks) {
            acc0 = __builtin_amdgcn_mfma_f32_16x16x32_bf16(a[ks], bfr0[ks], acc0, 0, 0, 0);
            acc1 = __builtin_amdgcn_mfma_f32_16x16x32_bf16(a[ks], bfr1[ks], acc1, 0, 0, 0);
        }

        #pragma unroll
        for (int i = 0; i < 4; ++i) {
            int   row = quad * 4 + i;
            float g   = sgate[buf][row];
            ctile[buf][row * CSTRIDE + o0] = f2bf(g * (acc0[i] + be0));
            ctile[buf][row * CSTRIDE + o1] = f2bf(g * (acc1[i] + be1));
        }

        // publish next tile (register bounce -> LDS), barrier, wide store
        if (more) {
            if (tid < 16) { stok[buf ^ 1][tid] = nmt; sgate[buf ^ 1][tid] = nmg; }
            *(bf16x8*)&atile[buf ^ 1][r0i * TOKSTRIDE + s0i * 8] = nx0;
            if (has1) *(bf16x8*)&atile[buf ^ 1][r1i * TOKSTRIDE + s1i * 8] = nx1;
        }
        __syncthreads();

        {
            int row = tid >> 4, chk = tid & 15;
            int raw = stok[buf][row];
            int t    = raw & 0x1FFFF;
            int slot = raw >> 20;
            *(bf16x8*)(slab + (size_t)slot * SLABROWS * DOUT
                            + (size_t)t * DOUT + chk * 8) =
                *(const bf16x8*)&ctile[buf][row * CSTRIDE + chk * 8];
        }
    }
}

// ---------------- K3: shared GEMM, B dbuf + slab prefetch; 16 tokens/block ----
// grid 4096 = (b,h) x wq; 4 waves each cover 2 n-blocks of one 16-token M-tile
__global__ __launch_bounds__(256)
void k3_shared(const unsigned short* __restrict__ tokbuf,
               const unsigned short* __restrict__ wt,
               const unsigned short* __restrict__ slab,
               const float* __restrict__ b_shared,
               float* __restrict__ out)
{
    __shared__ float out_lds[16 * 129];       // 8.3 KB

    const int tid  = threadIdx.x;
    const int bid  = blockIdx.x;
    const int bh   = bid >> 2;
    const int wq   = bid & 3;
    const int b    = bh >> 6;
    const int h    = bh & 63;
    const int wave = tid >> 6, lane = tid & 63;
    const int m16  = lane & 15, quad = lane >> 4;
    const int t0   = bh * 64 + wq * 16;       // first token of this block

    // prefetch slab contributions early (overlap with GEMM below)
    bf16x8 pv0, pv1;
    {
        const unsigned short* s0 = slab;
        const unsigned short* s1 = slab + (size_t)SLABROWS * DOUT;
        int tl = tid >> 4, chk = tid & 15;    // 256 = 16 tokens x 16 chunks
        size_t gt = (size_t)t0 + tl;
        pv0 = *(const bf16x8*)(s0 + gt * DOUT + chk * 8);
        pv1 = *(const bf16x8*)(s1 + gt * DOUT + chk * 8);
    }

    const unsigned short* ap =
        tokbuf + (size_t)(t0 + m16) * 192 + quad * 8;
    bf16x8 a[6];
    #pragma unroll
    for (int ks = 0; ks < 6; ++ks) a[ks] = *(const bf16x8*)(ap + ks * 32);

    const unsigned short* wsh = wt + (size_t)8 * DOUT * DIN;  // shared = mat 8

    // B double-buffer: each wave owns n-blocks wave*2 .. wave*2+1
    bf16x8 bcur[6], bnxt[6];
    {
        int o = (wave * 2 + 0) * 16 + m16;
        const unsigned short* bp = wsh + (size_t)o * DIN + quad * 8;
        #pragma unroll
        for (int ks = 0; ks < 6; ++ks) bcur[ks] = *(const bf16x8*)(bp + ks * 32);
    }
    #pragma unroll
    for (int nb2 = 0; nb2 < 2; ++nb2) {
        if (nb2 < 1) {
            int on = (wave * 2 + 1) * 16 + m16;
            const unsigned short* bp = wsh + (size_t)on * DIN + quad * 8;
            #pragma unroll
            for (int ks = 0; ks < 6; ++ks) bnxt[ks] = *(const bf16x8*)(bp + ks * 32);
        }
        int o = (wave * 2 + nb2) * 16 + m16;
        f32x4 acc = {0.f, 0.f, 0.f, 0.f};
        #pragma unroll
        for (int ks = 0; ks < 6; ++ks)
            acc = __builtin_amdgcn_mfma_f32_16x16x32_bf16(a[ks], bcur[ks], acc, 0, 0, 0);
        float bs = b_shared[o];
        #pragma unroll
        for (int i = 0; i < 4; ++i) {
            int tloc = quad * 4 + i;          // C/D: col=lane&15, row=quad*4+i
            out_lds[tloc * 129 + o] = acc[i] + bs;
        }
        #pragma unroll
        for (int ks = 0; ks < 6; ++ks) bcur[ks] = bnxt[ks];
    }
    __syncthreads();

    // combine prefetched slab values
    {
        int tl = tid >> 4, chk = tid & 15;
        float* dst = &out_lds[tl * 129 + chk * 8];
        #pragma unroll
        for (int q = 0; q < 8; ++q)
            dst[q] += bf2f((unsigned short)pv0[q]) + bf2f((unsigned short)pv1[q]);
    }
    __syncthreads();

    // out[b, o, h, w]: lanes sweep w-local -> coalesced (64B segments)
    float* outp = out + ((size_t)b * DOUT) * 4096 + h * 64 + wq * 16;
    for (int idx = tid; idx < 16 * DOUT; idx += 256) {
        int wloc = idx & 15, o = idx >> 4;
        outp[(size_t)o * 4096 + wloc] = out_lds[wloc * 129 + o];
    }
}

// ================== fallback (round-3 fused path, needs only 442 KB ws) ======
#define OUTSTRIDE 129
#define MAXROWS 320
#define MAXTILES 20

__global__ __launch_bounds__(256)
void moe_conv2d_mfma(const float* __restrict__ x,
                     const float* __restrict__ conv_w,
                     const float* __restrict__ router_w,
                     const unsigned short* __restrict__ wt,
                     const float* __restrict__ b_experts,
                     const float* __restrict__ b_shared,
                     float* __restrict__ out)
{
    __shared__ __attribute__((aligned(16))) unsigned short tokbf[64 * TOKSTRIDE];
    __shared__ float out_lds[64 * OUTSTRIDE];
    __shared__ float rw[DIN * NEXP];
    __shared__ float logits[64 * LOGSTRIDE];
    __shared__ float sg0[64], sg1[64];
    __shared__ int   se0[64], se1[64];
    __shared__ int   rowtok[MAXROWS];
    __shared__ float rowgate[MAXROWS];
    __shared__ int   cbuf[NMAT];
    __shared__ int   tilexp[MAXTILES], tilebase[MAXTILES];
    __shared__ int   ntiles_s;

    const int tid = threadIdx.x;
    const int bh  = blockIdx.x;
    const int b   = bh >> 6;
    const int h   = bh & 63;

    for (int idx = tid; idx < DIN * NEXP; idx += 256) rw[idx] = router_w[idx];
    for (int idx = tid; idx < 64 * LOGSTRIDE; idx += 256) logits[idx] = 0.f;
    __syncthreads();
    {
        const int w  = tid & 63;
        const int fq = tid >> 6;
        float lacc[8];
        #pragma unroll
        for (int e = 0; e < 8; ++e) lacc[e] = 0.f;
        for (int i = 0; i < 48; ++i) {
            int f = i * 4 + fq;
            int c = f / 3;
            const float* wp    = conv_w + f * 9;
            const float* xbase = x + ((size_t)(b * 64 + c) * 64) * 64;
            float acc = 0.f;
            #pragma unroll
            for (int kh = 0; kh < 3; ++kh) {
                int hh = h + kh - 1;
                if (hh < 0 || hh > 63) continue;
                const float* xrow = xbase + hh * 64;
                #pragma unroll
                for (int kw = 0; kw < 3; ++kw) {
                    int ww = w + kw - 1;
                    if (ww < 0 || ww > 63) continue;
                    acc += xrow[ww] * wp[kh * 3 + kw];
                }
            }
            tokbf[w * TOKSTRIDE + f] = f2bf(acc);
            const float* rwf = rw + f * 8;
            #pragma unroll
            for (int e = 0; e < 8; ++e) lacc[e] += acc * rwf[e];
        }
        #pragma unroll
        for (int e = 0; e < 8; ++e)
            atomicAdd(&logits[w * LOGSTRIDE + e], lacc[e]);
    }
    __syncthreads();
    if (tid < 64) {
        int w = tid;
        float l[8];
        #pragma unroll
        for (int e = 0; e < 8; ++e) l[e] = logits[w * LOGSTRIDE + e];
        int e0 = 0; float l0 = l[0];
        #pragma unroll
        for (int e = 1; e < 8; ++e) if (l[e] > l0) { l0 = l[e]; e0 = e; }
        int e1 = -1; float l1 = -INFINITY;
        #pragma unroll
        for (int e = 0; e < 8; ++e) {
            if (e == e0) continue;
            if (l[e] > l1) { l1 = l[e]; e1 = e; }
        }
        float g0 = 1.f / (1.f + expf(l1 - l0));
        sg0[w] = g0; sg1[w] = 1.f - g0;
        se0[w] = e0; se1[w] = e1;
    }
    __syncthreads();
    for (int idx = tid; idx < 64 * DOUT; idx += 256) {
        int t = idx >> 7, o = idx & 127;
        out_lds[t * OUTSTRIDE + o] = b_shared[o]
            + sg0[t] * b_experts[se0[t] * DOUT + o]
            + sg1[t] * b_experts[se1[t] * DOUT + o];
    }
    if (tid < 8) {
        int c = 0;
        for (int t = 0; t < 64; ++t) c += (se0[t] == tid) + (se1[t] == tid);
        cbuf[tid] = c;
    } else if (tid == 8) cbuf[8] = 64;
    __syncthreads();
    if (tid < NMAT) {
        int e = tid;
        int start = 0, tb = 0;
        for (int e2 = 0; e2 < e; ++e2) {
            int ce = cbuf[e2];
            int tl = (ce + 15) >> 4;
            start += tl << 4; tb += tl;
        }
        int ce = cbuf[e];
        int tl = (ce + 15) >> 4;
        for (int j = 0; j < tl; ++j) { tilexp[tb + j] = e; tilebase[tb + j] = start + (j << 4); }
        if (e == 8) ntiles_s = tb + tl;
        int j = 0;
        if (e < 8) {
            for (int t = 0; t < 64; ++t) {
                if (se0[t] == e) { rowtok[start + j] = t; rowgate[start + j] = sg0[t]; ++j; }
                if (se1[t] == e) { rowtok[start + j] = t; rowgate[start + j] = sg1[t]; ++j; }
            }
        } else {
            for (int t = 0; t < 64; ++t) { rowtok[start + j] = t; rowgate[start + j] = 1.f; ++j; }
        }
        for (; j < (tl << 4); ++j) { rowtok[start + j] = 0; rowgate[start + j] = 0.f; }
    }
    __syncthreads();
    {
        const int wave = tid >> 6;
        const int lane = tid & 63;
        const int m16  = lane & 15;
        const int quad = lane >> 4;
        const int nt   = ntiles_s;
        for (int ti = wave; ti < nt; ti += 4) {
            int e    = tilexp[ti];
            int base = tilebase[ti];
            int tA = rowtok[base + m16];
            bf16x8 a[6];
            #pragma unroll
            for (int ks = 0; ks < 6; ++ks)
                a[ks] = *(const bf16x8*)(tokbf + tA * TOKSTRIDE + ks * 32 + quad * 8);
            int st[4]; float sgt[4];
            #pragma unroll
            for (int i2 = 0; i2 < 4; ++i2) {
                int r = base + quad * 4 + i2;
                st[i2] = rowtok[r]; sgt[i2] = rowgate[r];
            }
            const unsigned short* we = wt + (size_t)e * DOUT * DIN;
            for (int n = 0; n < 8; ++n) {
                const unsigned short* wp = we + (size_t)(n * 16 + m16) * DIN + quad * 8;
                f32x4 acc = {0.f, 0.f, 0.f, 0.f};
                #pragma unroll
                for (int ks = 0; ks < 6; ++ks) {
                    bf16x8 bfr2 = *(const bf16x8*)(wp + ks * 32);
                    acc = __builtin_amdgcn_mfma_f32_16x16x32_bf16(a[ks], bfr2, acc, 0, 0, 0);
                }
                int ncol = n * 16 + m16;
                #pragma unroll
                for (int i2 = 0; i2 < 4; ++i2)
                    atomicAdd(&out_lds[st[i2] * OUTSTRIDE + ncol], sgt[i2] * acc[i2]);
            }
        }
    }
    __syncthreads();
    {
        float* outp = out + (((size_t)b * DOUT) * 64 + h) * 64;
        for (int idx = tid; idx < 64 * DOUT; idx += 256) {
            int w = idx & 63, o = idx >> 6;
            outp[(size_t)o * 4096 + w] = out_lds[w * OUTSTRIDE + o];
        }
    }
}

__global__ __launch_bounds__(256)
void prep_weights_only(const float* __restrict__ w_experts,
                       const float* __restrict__ w_shared,
                       unsigned short* __restrict__ wt)
{
    int e = blockIdx.x;
    const float* src = (e < 8) ? (w_experts + (size_t)e * DIN * DOUT) : w_shared;
    unsigned short* dst = wt + (size_t)e * DOUT * DIN;
    for (int idx = threadIdx.x; idx < DOUT * DIN; idx += 256) {
        int n = idx / DIN, k = idx - n * DIN;
        dst[idx] = f2bf(src[k * DOUT + n]);
    }
}

// =============================================================================
extern "C" void kernel_launch(void* const* d_in, const int* in_sizes, int n_in,
                              void* d_out, int out_size, void* d_ws, size_t ws_size,
                              hipStream_t stream)
{
    const float* x         = (const float*)d_in[0];
    const float* conv_w    = (const float*)d_in[1];
    const float* router_w  = (const float*)d_in[2];
    const float* w_experts = (const float*)d_in[3];
    const float* b_experts = (const float*)d_in[4];
    const float* w_shared  = (const float*)d_in[5];
    const float* b_shared  = (const float*)d_in[6];
    float* out = (float*)d_out;
    char* ws = (char*)d_ws;

    if (ws_size >= WS_TOTAL) {
        unsigned short* tokbuf  = (unsigned short*)(ws + WS_TOK);
        unsigned short* wt      = (unsigned short*)(ws + WS_WT);
        int*            cnt     = (int*)(ws + WS_CNT);
        int*            rowtok  = (int*)(ws + WS_RT);
        float*          rowgate = (float*)(ws + WS_RG);
        unsigned short* slab    = (unsigned short*)(ws + WS_SLAB);
        float*          lpart   = (float*)(ws + WS_SLAB);   // aliased, see layout

        k1a_conv<<<dim3(4096), dim3(256), 0, stream>>>(
            x, conv_w, router_w, tokbuf, lpart, cnt);
        k1b_route<<<dim3(256), dim3(256), 0, stream>>>(
            lpart, cnt, rowtok, rowgate, w_experts, w_shared, wt);
        k4_routed<<<dim3(4096), dim3(256), 0, stream>>>(
            tokbuf, wt, b_experts, cnt, rowtok, rowgate, slab);
        k3_shared<<<dim3(4096), dim3(256), 0, stream>>>(
            tokbuf, wt, slab, b_shared, out);
    } else {
        // fallback: round-3 fused path (needs only 442 KB ws)
        unsigned short* wt = (unsigned short*)ws;
        prep_weights_only<<<dim3(NMAT), dim3(256), 0, stream>>>(w_experts, w_shared, wt);
        moe_conv2d_mfma<<<dim3(1024), dim3(256), 0, stream>>>(
            x, conv_w, router_w, wt, b_experts, b_shared, out);
    }
}

// Round 13
// 178.559 us; speedup vs baseline: 1.2573x; 1.2573x over previous
//
#include <hip/hip_runtime.h>
#include <math.h>

// Problem constants
#define BB   16
#define CC   64
#define DIN  192     // C*K
#define DOUT 128
#define NEXP 8
#define NMAT 9       // 8 routed + 1 shared
#define NTOK 65536   // B*H*W
#define CAP  65568   // per-expert bucket capacity
#define SLABROWS 65552  // NTOK + 16 (dump rows for padding)

#define TOKSTRIDE 200   // LDS bf16 token row stride
#define HALFSTRIDE 104  // LDS bf16 stride for 96-f half rows
#define LOGSTRIDE 9
#define CSTRIDE 136     // k4 LDS C-tile stride (shorts)

typedef short bf16x8 __attribute__((ext_vector_type(8)));
typedef float f32x4  __attribute__((ext_vector_type(4)));

// ---- workspace layout (bytes) ----
#define WS_TOK   0u          // bf16[NTOK][192]            25165824
#define WS_WT    25165824u   // bf16[9][128][192]          442368
#define WS_CNT   25608192u   // int[16]                    64
#define WS_RT    25608256u   // int[8][CAP] token|slot<<20 2098176
#define WS_RG    27706432u   // float[8][CAP]              2098176
#define WS_SLAB  29804608u   // bf16[2][SLABROWS][128]     33562624
#define WS_TOTAL 63367232u
// lpart (fp32[2][NTOK][8] = 4 MB) aliases the START of WS_SLAB: written by
// k1a, read by k1b, then fully overwritten by k4 before k3 reads slab.
#define LPHALF 524288        // floats per channel-half

__device__ __forceinline__ unsigned short f2bf(float f) {
    union { float f; unsigned u; } v; v.f = f;
    unsigned u = v.u;
    u += 0x7fffu + ((u >> 16) & 1u);   // RNE (inputs finite)
    return (unsigned short)(u >> 16);
}
__device__ __forceinline__ float bf2f(unsigned short s) {
    union { unsigned u; float f; } v; v.u = ((unsigned)s) << 16;
    return v.f;
}

// ---------------- K1a: conv + router partials, LDS x-stage, pipelined ---------
// grid 2048 = (b,h) x chalf; x staged per 16-channel chunk via 3 float4
// coalesced loads/thread (one vmcnt wait per chunk); chunk1 loads issued
// before chunk0 compute (register bounce) so latency overlaps FMA work.
// NOTE (r12 lesson): tokbuf segments must stay 64B-aligned — half-split gives
// 192 B at offset chalf*192 (aligned); quarter-split (96 B) caused 2x write
// amplification (WRITE_SIZE 29 -> 57 MB).
__global__ __launch_bounds__(256)
void k1a_conv(const float* __restrict__ x,
              const float* __restrict__ conv_w,
              const float* __restrict__ router_w,
              unsigned short* __restrict__ tokbuf,
              float* __restrict__ lpart,
              int* __restrict__ cnt)
{
    __shared__ __attribute__((aligned(16))) unsigned short tokbf[64 * HALFSTRIDE];
    __shared__ float logits[64 * LOGSTRIDE];
    __shared__ __attribute__((aligned(16))) float xs[2][16 * 192];  // 24.6 KB

    const int tid   = threadIdx.x;
    const int bid   = blockIdx.x;
    const int bh    = bid >> 1;
    const int chalf = bid & 1;
    const int b     = bh >> 6;
    const int h     = bh & 63;

    if (bid == 0 && tid < 16) cnt[tid] = 0;
    for (int idx = tid; idx < 64 * LOGSTRIDE; idx += 256) logits[idx] = 0.f;

    const int   h0  = (h > 0)  ? (h - 1) : 0;
    const int   h2  = (h < 63) ? (h + 1) : 63;
    const float mh0 = (h > 0)  ? 1.f : 0.f;
    const float mh2 = (h < 63) ? 1.f : 0.f;

    // staging map: idx = q*256+tid in [0,768): c=idx/48, row=(idx%48)/16,
    // seg=idx%16 -> float4 at x[b][cbase+c][hrow][seg*4]
    const int sc[3]  = { (0*256+tid)/48, (1*256+tid)/48, (2*256+tid)/48 };
    int srow[3], sseg[3];
    #pragma unroll
    for (int q = 0; q < 3; ++q) {
        int rem = (q * 256 + tid) % 48;
        srow[q] = rem >> 4; sseg[q] = rem & 15;
    }
    const float* xb = x + (size_t)b * CC * 4096;

    // ---- stage chunk 0 ----
    {
        float4 st[3];
        #pragma unroll
        for (int q = 0; q < 3; ++q) {
            int hh = (srow[q] == 0) ? h0 : ((srow[q] == 1) ? h : h2);
            st[q] = *(const float4*)(xb + ((size_t)(chalf * 32 + sc[q]) * 64 + hh) * 64
                                        + sseg[q] * 4);
        }
        #pragma unroll
        for (int q = 0; q < 3; ++q)
            *(float4*)&xs[0][sc[q] * 192 + srow[q] * 64 + sseg[q] * 4] = st[q];
    }
    __syncthreads();

    const int w  = tid & 63;
    const int cq = __builtin_amdgcn_readfirstlane(tid >> 6); // wave-uniform

    const int   wm  = (w == 0)  ? 0  : (w - 1);
    const int   wp  = (w == 63) ? 63 : (w + 1);
    const float mwm = (w == 0)  ? 0.f : 1.f;
    const float mwp = (w == 63) ? 0.f : 1.f;

    float lacc[8];
    #pragma unroll
    for (int e = 0; e < 8; ++e) lacc[e] = 0.f;

    // ---- issue chunk-1 loads (vmcnt wait lands after chunk-0 compute) ----
    float4 st1[3];
    #pragma unroll
    for (int q = 0; q < 3; ++q) {
        int hh = (srow[q] == 0) ? h0 : ((srow[q] == 1) ? h : h2);
        st1[q] = *(const float4*)(xb + ((size_t)(chalf * 32 + 16 + sc[q]) * 64 + hh) * 64
                                     + sseg[q] * 4);
    }

    // ---- compute both chunks ----
    #pragma unroll
    for (int ch = 0; ch < 2; ++ch) {
        const float* xsc = xs[ch];
        #pragma unroll
        for (int i = 0; i < 4; ++i) {
            int cc = cq * 4 + i;                       // channel within chunk
            int cl = ch * 16 + cc;                     // channel within half
            const float* r0 = xsc + cc * 192;
            const float* r1 = r0 + 64;
            const float* r2 = r0 + 128;
            float x00 = r0[wm], x01 = r0[w], x02 = r0[wp];
            float x10 = r1[wm], x11 = r1[w], x12 = r1[wp];
            float x20 = r2[wm], x21 = r2[w], x22 = r2[wp];
            x00 *= mh0 * mwm; x01 *= mh0; x02 *= mh0 * mwp;
            x10 *= mwm;                    x12 *= mwp;
            x20 *= mh2 * mwm; x21 *= mh2; x22 *= mh2 * mwp;

            #pragma unroll
            for (int j = 0; j < 3; ++j) {
                int fl = 3 * cl + j;                   // local f (0..95)
                int f  = chalf * 96 + fl;              // global f, wave-uniform
                const float* w9 = conv_w + f * 9;      // scalar loads (L2-hot)
                float acc = x00 * w9[0] + x01 * w9[1] + x02 * w9[2]
                          + x10 * w9[3] + x11 * w9[4] + x12 * w9[5]
                          + x20 * w9[6] + x21 * w9[7] + x22 * w9[8];
                tokbf[w * HALFSTRIDE + fl] = f2bf(acc);
                const float* rwf = router_w + f * 8;   // scalar loads
                #pragma unroll
                for (int e = 0; e < 8; ++e) lacc[e] += acc * rwf[e];
            }
        }
        if (ch == 0) {
            // publish chunk 1 (register bounce -> LDS), then barrier
            #pragma unroll
            for (int q = 0; q < 3; ++q)
                *(float4*)&xs[1][sc[q] * 192 + srow[q] * 64 + sseg[q] * 4] = st1[q];
            __syncthreads();
        }
    }

    #pragma unroll
    for (int e = 0; e < 8; ++e)
        atomicAdd(&logits[w * LOGSTRIDE + e], lacc[e]);  // 4 threads/(w,e)
    __syncthreads();

    // partial logits -> global (coalesced)
    for (int idx = tid; idx < 512; idx += 256) {
        int wtok = idx >> 3, e = idx & 7;
        lpart[(size_t)chalf * LPHALF + ((size_t)bh * 64 + wtok) * 8 + e] =
            logits[wtok * LOGSTRIDE + e];
    }
    // tokens LDS -> global (bf16x8 chunks; 64 rows x 12 chunks; 192B aligned)
    for (int idx = tid; idx < 768; idx += 256) {
        int row = idx / 12, seg = idx - row * 12;
        *(bf16x8*)(tokbuf + (size_t)(bh * 64 + row) * 192 + chalf * 96 + seg * 8) =
            *(const bf16x8*)(tokbf + row * HALFSTRIDE + seg * 8);
    }
}

// ---------------- K1b: sum halves, top-2, parallel rank append + wt prep ------
__global__ __launch_bounds__(256)
void k1b_route(const float* __restrict__ lpart,
               int* __restrict__ cnt,
               int* __restrict__ rowtok, float* __restrict__ rowgate,
               const float* __restrict__ w_experts,
               const float* __restrict__ w_shared,
               unsigned short* __restrict__ wt)
{
    __shared__ int lcnt[8];
    __shared__ int lbase[8];

    const int tid = threadIdx.x;
    const int blk = blockIdx.x;
    const int t   = blk * 256 + tid;          // 256 blocks x 256 tokens

    if (tid < 8) lcnt[tid] = 0;
    __syncthreads();

    const float* p0 = lpart + (size_t)t * 8;
    const float* p1 = lpart + LPHALF + (size_t)t * 8;
    float l[8];
    #pragma unroll
    for (int e = 0; e < 8; ++e) l[e] = p0[e] + p1[e];

    // fp32 exact top-2; strict > keeps lowest index on ties (lax.top_k)
    int e0 = 0; float l0 = l[0];
    #pragma unroll
    for (int e = 1; e < 8; ++e) if (l[e] > l0) { l0 = l[e]; e0 = e; }
    int e1 = -1; float l1 = -INFINITY;
    #pragma unroll
    for (int e = 0; e < 8; ++e) {
        if (e == e0) continue;
        if (l[e] > l1) { l1 = l[e]; e1 = e; }
    }
    float g0 = 1.f / (1.f + expf(l1 - l0));   // softmax Z cancels in renorm
    float g1 = 1.f - g0;

    // local ranks (LDS atomics), one global reservation per expert
    int r0 = atomicAdd(&lcnt[e0], 1);
    int r1 = atomicAdd(&lcnt[e1], 1);
    __syncthreads();
    if (tid < 8) lbase[tid] = atomicAdd(&cnt[tid], lcnt[tid]);
    __syncthreads();

    int p0i = e0 * CAP + lbase[e0] + r0;
    int p1i = e1 * CAP + lbase[e1] + r1;
    rowtok[p0i]  = t;
    rowgate[p0i] = g0;
    rowtok[p1i]  = t | (1 << 20);
    rowgate[p1i] = g1;

    // weight transpose slice: 864 elems/block of wt[e][n][k] = src[e][k][n]
    {
        int base = blk * 864;
        for (int q = 0; q < 4; ++q) {
            int idx = base + q * 256 + tid;
            if (idx < 221184 && (q * 256 + tid) < 864) {
                int e = idx / 24576, rem = idx - e * 24576;
                int n = rem / DIN,  k  = rem - n * DIN;
                const float* src = (e < 8) ? (w_experts + (size_t)e * DIN * DOUT)
                                           : w_shared;
                wt[idx] = f2bf(src[k * DOUT + n]);
            }
        }
    }
}

// ---------------- K4: routed GEMM, register-bounced A pipeline ----------------
// grid 2048 = 8 experts x 256 jb. Next tile's rows are loaded into REGISTERS
// before this tile's MFMA (vmcnt wait lands after compute), then ds_written.
__global__ __launch_bounds__(256)
void k4_routed(const unsigned short* __restrict__ tokbuf,
               const unsigned short* __restrict__ wt,
               const float* __restrict__ b_experts,
               const int* __restrict__ cnt,
               const int* __restrict__ rowtok, const float* __restrict__ rowgate,
               unsigned short* __restrict__ slab)
{
    __shared__ __attribute__((aligned(16))) unsigned short atile[2][16 * TOKSTRIDE]; // 12.8 KB
    __shared__ __attribute__((aligned(16))) unsigned short ctile[2][16 * CSTRIDE];   // 8.7 KB
    __shared__ int   stok[2][16];
    __shared__ float sgate[2][16];

    const int tid  = threadIdx.x;
    const int e    = blockIdx.x >> 8;         // 0..7
    const int jb   = blockIdx.x & 255;
    const int wave = tid >> 6;
    const int lane = tid & 63;
    const int m16  = lane & 15, quad = lane >> 4;
    const int o0   = (wave * 2 + 0) * 16 + m16;
    const int o1   = (wave * 2 + 1) * 16 + m16;

    const unsigned short* wb = wt + (size_t)e * DOUT * DIN;
    bf16x8 bfr0[6], bfr1[6];
    #pragma unroll
    for (int ks = 0; ks < 6; ++ks) {
        bfr0[ks] = *(const bf16x8*)(wb + (size_t)o0 * DIN + ks * 32 + quad * 8);
        bfr1[ks] = *(const bf16x8*)(wb + (size_t)o1 * DIN + ks * 32 + quad * 8);
    }
    const float be0 = b_experts[e * DOUT + o0];
    const float be1 = b_experts[e * DOUT + o1];

    const int cnt_e  = cnt[e];
    const int ntiles = (cnt_e + 15) >> 4;
    const int*   rt = rowtok  + e * CAP;
    const float* rg = rowgate + e * CAP;

    // staging map: chunk idx = tid (+256): row=idx/24, seg=idx%24
    const int r0i = tid / 24,        s0i = tid - r0i * 24;
    const int r1i = (tid + 256) / 24, s1i = (tid + 256) - r1i * 24;
    const bool has1 = (tid + 256) < 384;

    // ---- prologue: stage tile jb into buf 0 ----
    if (jb < ntiles) {
        int base = jb * 16;
        if (tid < 16) {
            int r = base + tid;
            bool ok = (r < cnt_e);
            stok[0][tid]  = ok ? rt[r] : NTOK;
            sgate[0][tid] = ok ? rg[r] : 0.f;
        }
        {
            int ra = base + r0i;
            int raw = (ra < cnt_e) ? rt[ra] : NTOK;
            *(bf16x8*)&atile[0][r0i * TOKSTRIDE + s0i * 8] =
                *(const bf16x8*)(tokbuf + (size_t)(raw & 0x1FFFF) * 192 + s0i * 8);
            if (has1) {
                int rb = base + r1i;
                int rawb = (rb < cnt_e) ? rt[rb] : NTOK;
                *(bf16x8*)&atile[0][r1i * TOKSTRIDE + s1i * 8] =
                    *(const bf16x8*)(tokbuf + (size_t)(rawb & 0x1FFFF) * 192 + s1i * 8);
            }
        }
    }
    __syncthreads();

    int buf = 0;
    for (int j = jb; j < ntiles; j += 256, buf ^= 1) {
        const int jn = j + 256;
        const bool more = (jn < ntiles);

        // ---- issue next tile's global loads into registers (no use yet) ----
        bf16x8 nx0 = {0,0,0,0,0,0,0,0}, nx1 = {0,0,0,0,0,0,0,0};
        int nmt = NTOK; float nmg = 0.f;
        if (more) {
            int base = jn * 16;
            if (tid < 16) {
                int r = base + tid;
                bool ok = (r < cnt_e);
                nmt = ok ? rt[r] : NTOK;
                nmg = ok ? rg[r] : 0.f;
            }
            int ra = base + r0i;
            int rawa = (ra < cnt_e) ? rt[ra] : NTOK;
            nx0 = *(const bf16x8*)(tokbuf + (size_t)(rawa & 0x1FFFF) * 192 + s0i * 8);
            if (has1) {
                int rb = base + r1i;
                int rawb = (rb < cnt_e) ? rt[rb] : NTOK;
                nx1 = *(const bf16x8*)(tokbuf + (size_t)(rawb & 0x1FFFF) * 192 + s1i * 8);
            }
        }

        // ---- compute current tile ----
        bf16x8 a[6];
        #pragma unroll
        for (int ks = 0; ks < 6; ++ks)
            a[ks] = *(const bf16x8*)&atile[buf][m16 * TOKSTRIDE + ks * 32 + quad * 8];

        f32x4 acc0 = {0.f, 0.f, 0.f, 0.f};
        f32x4 acc1 = {0.f, 0.f, 0.f, 0.f};
        #pragma unroll
        for (int ks = 0; ks < 6; ++ks) {
            acc0 = __builtin_amdgcn_mfma_f32_16x16x32_bf16(a[ks], bfr0[ks], acc0, 0, 0, 0);
            acc1 = __builtin_amdgcn_mfma_f32_16x16x32_bf16(a[ks], bfr1[ks], acc1, 0, 0, 0);
        }

        #pragma unroll
        for (int i = 0; i < 4; ++i) {
            int   row = quad * 4 + i;
            float g   = sgate[buf][row];
            ctile[buf][row * CSTRIDE + o0] = f2bf(g * (acc0[i] + be0));
            ctile[buf][row * CSTRIDE + o1] = f2bf(g * (acc1[i] + be1));
        }

        // ---- publish next tile (register bounce -> LDS), barrier, store ----
        if (more) {
            if (tid < 16) { stok[buf ^ 1][tid] = nmt; sgate[buf ^ 1][tid] = nmg; }
            *(bf16x8*)&atile[buf ^ 1][r0i * TOKSTRIDE + s0i * 8] = nx0;
            if (has1) *(bf16x8*)&atile[buf ^ 1][r1i * TOKSTRIDE + s1i * 8] = nx1;
        }
        __syncthreads();

        {
            int row = tid >> 4, chk = tid & 15;
            int raw = stok[buf][row];
            int t    = raw & 0x1FFFF;
            int slot = raw >> 20;
            *(bf16x8*)(slab + (size_t)slot * SLABROWS * DOUT
                            + (size_t)t * DOUT + chk * 8) =
                *(const bf16x8*)&ctile[buf][row * CSTRIDE + chk * 8];
        }
    }
}

// ---------------- K3: shared GEMM, B double-buffered + slab prefetch ----------
// grid 2048 = (b,h) x whalf; 32 tokens; 4 waves = 2 M-tiles x 2 N-halves
__global__ __launch_bounds__(256)
void k3_shared(const unsigned short* __restrict__ tokbuf,
               const unsigned short* __restrict__ wt,
               const unsigned short* __restrict__ slab,
               const float* __restrict__ b_shared,
               float* __restrict__ out)
{
    __shared__ float out_lds[32 * 129];       // 16.5 KB

    const int tid  = threadIdx.x;
    const int bid  = blockIdx.x;
    const int bh   = bid >> 1;
    const int wh   = bid & 1;
    const int b    = bh >> 6;
    const int h    = bh & 63;
    const int wave = tid >> 6, lane = tid & 63;
    const int mt   = wave >> 1, nh = wave & 1;
    const int m16  = lane & 15, quad = lane >> 4;
    const int t0   = bh * 64 + wh * 32;       // first token of this block

    // prefetch slab contributions early (overlap with GEMM below)
    bf16x8 pv0[2], pv1[2];
    {
        const unsigned short* s0 = slab;
        const unsigned short* s1 = slab + (size_t)SLABROWS * DOUT;
        #pragma unroll
        for (int it = 0; it < 2; ++it) {
            int idx = it * 256 + tid;          // 512 = 32 tokens x 16 chunks
            int tl = idx >> 4, chk = idx & 15;
            size_t gt = (size_t)t0 + tl;
            pv0[it] = *(const bf16x8*)(s0 + gt * DOUT + chk * 8);
            pv1[it] = *(const bf16x8*)(s1 + gt * DOUT + chk * 8);
        }
    }

    const unsigned short* ap =
        tokbuf + (size_t)(t0 + mt * 16 + m16) * 192 + quad * 8;
    bf16x8 a[6];
    #pragma unroll
    for (int ks = 0; ks < 6; ++ks) a[ks] = *(const bf16x8*)(ap + ks * 32);

    const unsigned short* wsh = wt + (size_t)8 * DOUT * DIN;  // shared = mat 8

    // B double-buffer: load n-block nb2+1 while MFMA of nb2 runs
    bf16x8 bcur[6], bnxt[6];
    {
        int o = (nh * 4 + 0) * 16 + m16;
        const unsigned short* bp = wsh + (size_t)o * DIN + quad * 8;
        #pragma unroll
        for (int ks = 0; ks < 6; ++ks) bcur[ks] = *(const bf16x8*)(bp + ks * 32);
    }
    #pragma unroll
    for (int nb2 = 0; nb2 < 4; ++nb2) {
        if (nb2 < 3) {
            int on = (nh * 4 + nb2 + 1) * 16 + m16;
            const unsigned short* bp = wsh + (size_t)on * DIN + quad * 8;
            #pragma unroll
            for (int ks = 0; ks < 6; ++ks) bnxt[ks] = *(const bf16x8*)(bp + ks * 32);
        }
        int o = (nh * 4 + nb2) * 16 + m16;
        f32x4 acc = {0.f, 0.f, 0.f, 0.f};
        #pragma unroll
        for (int ks = 0; ks < 6; ++ks)
            acc = __builtin_amdgcn_mfma_f32_16x16x32_bf16(a[ks], bcur[ks], acc, 0, 0, 0);
        float bs = b_shared[o];
        #pragma unroll
        for (int i = 0; i < 4; ++i) {
            int tloc = mt * 16 + quad * 4 + i;
            out_lds[tloc * 129 + o] = acc[i] + bs;
        }
        #pragma unroll
        for (int ks = 0; ks < 6; ++ks) bcur[ks] = bnxt[ks];
    }
    __syncthreads();

    // combine prefetched slab values
    #pragma unroll
    for (int it = 0; it < 2; ++it) {
        int idx = it * 256 + tid;
        int tl = idx >> 4, chk = idx & 15;
        float* dst = &out_lds[tl * 129 + chk * 8];
        #pragma unroll
        for (int q = 0; q < 8; ++q)
            dst[q] += bf2f((unsigned short)pv0[it][q])
                    + bf2f((unsigned short)pv1[it][q]);
    }
    __syncthreads();

    // out[b, o, h, w]: lanes sweep w-local -> coalesced
    float* outp = out + ((size_t)b * DOUT) * 4096 + h * 64 + wh * 32;
    for (int idx = tid; idx < 32 * DOUT; idx += 256) {
        int wloc = idx & 31, o = idx >> 5;
        outp[(size_t)o * 4096 + wloc] = out_lds[wloc * 129 + o];
    }
}

// ================== fallback (round-3 fused path, needs only 442 KB ws) ======
#define OUTSTRIDE 129
#define MAXROWS 320
#define MAXTILES 20

__global__ __launch_bounds__(256)
void moe_conv2d_mfma(const float* __restrict__ x,
                     const float* __restrict__ conv_w,
                     const float* __restrict__ router_w,
                     const unsigned short* __restrict__ wt,
                     const float* __restrict__ b_experts,
                     const float* __restrict__ b_shared,
                     float* __restrict__ out)
{
    __shared__ __attribute__((aligned(16))) unsigned short tokbf[64 * TOKSTRIDE];
    __shared__ float out_lds[64 * OUTSTRIDE];
    __shared__ float rw[DIN * NEXP];
    __shared__ float logits[64 * LOGSTRIDE];
    __shared__ float sg0[64], sg1[64];
    __shared__ int   se0[64], se1[64];
    __shared__ int   rowtok[MAXROWS];
    __shared__ float rowgate[MAXROWS];
    __shared__ int   cbuf[NMAT];
    __shared__ int   tilexp[MAXTILES], tilebase[MAXTILES];
    __shared__ int   ntiles_s;

    const int tid = threadIdx.x;
    const int bh  = blockIdx.x;
    const int b   = bh >> 6;
    const int h   = bh & 63;

    for (int idx = tid; idx < DIN * NEXP; idx += 256) rw[idx] = router_w[idx];
    for (int idx = tid; idx < 64 * LOGSTRIDE; idx += 256) logits[idx] = 0.f;
    __syncthreads();
    {
        const int w  = tid & 63;
        const int fq = tid >> 6;
        float lacc[8];
        #pragma unroll
        for (int e = 0; e < 8; ++e) lacc[e] = 0.f;
        for (int i = 0; i < 48; ++i) {
            int f = i * 4 + fq;
            int c = f / 3;
            const float* wp    = conv_w + f * 9;
            const float* xbase = x + ((size_t)(b * 64 + c) * 64) * 64;
            float acc = 0.f;
            #pragma unroll
            for (int kh = 0; kh < 3; ++kh) {
                int hh = h + kh - 1;
                if (hh < 0 || hh > 63) continue;
                const float* xrow = xbase + hh * 64;
                #pragma unroll
                for (int kw = 0; kw < 3; ++kw) {
                    int ww = w + kw - 1;
                    if (ww < 0 || ww > 63) continue;
                    acc += xrow[ww] * wp[kh * 3 + kw];
                }
            }
            tokbf[w * TOKSTRIDE + f] = f2bf(acc);
            const float* rwf = rw + f * 8;
            #pragma unroll
            for (int e = 0; e < 8; ++e) lacc[e] += acc * rwf[e];
        }
        #pragma unroll
        for (int e = 0; e < 8; ++e)
            atomicAdd(&logits[w * LOGSTRIDE + e], lacc[e]);
    }
    __syncthreads();
    if (tid < 64) {
        int w = tid;
        float l[8];
        #pragma unroll
        for (int e = 0; e < 8; ++e) l[e] = logits[w * LOGSTRIDE + e];
        int e0 = 0; float l0 = l[0];
        #pragma unroll
        for (int e = 1; e < 8; ++e) if (l[e] > l0) { l0 = l[e]; e0 = e; }
        int e1 = -1; float l1 = -INFINITY;
        #pragma unroll
        for (int e = 0; e < 8; ++e) {
            if (e == e0) continue;
            if (l[e] > l1) { l1 = l[e]; e1 = e; }
        }
        float g0 = 1.f / (1.f + expf(l1 - l0));
        sg0[w] = g0; sg1[w] = 1.f - g0;
        se0[w] = e0; se1[w] = e1;
    }
    __syncthreads();
    for (int idx = tid; idx < 64 * DOUT; idx += 256) {
        int t = idx >> 7, o = idx & 127;
        out_lds[t * OUTSTRIDE + o] = b_shared[o]
            + sg0[t] * b_experts[se0[t] * DOUT + o]
            + sg1[t] * b_experts[se1[t] * DOUT + o];
    }
    if (tid < 8) {
        int c = 0;
        for (int t = 0; t < 64; ++t) c += (se0[t] == tid) + (se1[t] == tid);
        cbuf[tid] = c;
    } else if (tid == 8) cbuf[8] = 64;
    __syncthreads();
    if (tid < NMAT) {
        int e = tid;
        int start = 0, tb = 0;
        for (int e2 = 0; e2 < e; ++e2) {
            int ce = cbuf[e2];
            int tl = (ce + 15) >> 4;
            start += tl << 4; tb += tl;
        }
        int ce = cbuf[e];
        int tl = (ce + 15) >> 4;
        for (int j = 0; j < tl; ++j) { tilexp[tb + j] = e; tilebase[tb + j] = start + (j << 4); }
        if (e == 8) ntiles_s = tb + tl;
        int j = 0;
        if (e < 8) {
            for (int t = 0; t < 64; ++t) {
                if (se0[t] == e) { rowtok[start + j] = t; rowgate[start + j] = sg0[t]; ++j; }
                if (se1[t] == e) { rowtok[start + j] = t; rowgate[start + j] = sg1[t]; ++j; }
            }
        } else {
            for (int t = 0; t < 64; ++t) { rowtok[start + j] = t; rowgate[start + j] = 1.f; ++j; }
        }
        for (; j < (tl << 4); ++j) { rowtok[start + j] = 0; rowgate[start + j] = 0.f; }
    }
    __syncthreads();
    {
        const int wave = tid >> 6;
        const int lane = tid & 63;
        const int m16  = lane & 15;
        const int quad = lane >> 4;
        const int nt   = ntiles_s;
        for (int ti = wave; ti < nt; ti += 4) {
            int e    = tilexp[ti];
            int base = tilebase[ti];
            int tA = rowtok[base + m16];
            bf16x8 a[6];
            #pragma unroll
            for (int ks = 0; ks < 6; ++ks)
                a[ks] = *(const bf16x8*)(tokbf + tA * TOKSTRIDE + ks * 32 + quad * 8);
            int st[4]; float sgt[4];
            #pragma unroll
            for (int i2 = 0; i2 < 4; ++i2) {
                int r = base + quad * 4 + i2;
                st[i2] = rowtok[r]; sgt[i2] = rowgate[r];
            }
            const unsigned short* we = wt + (size_t)e * DOUT * DIN;
            for (int n = 0; n < 8; ++n) {
                const unsigned short* wp = we + (size_t)(n * 16 + m16) * DIN + quad * 8;
                f32x4 acc = {0.f, 0.f, 0.f, 0.f};
                #pragma unroll
                for (int ks = 0; ks < 6; ++ks) {
                    bf16x8 bfr2 = *(const bf16x8*)(wp + ks * 32);
                    acc = __builtin_amdgcn_mfma_f32_16x16x32_bf16(a[ks], bfr2, acc, 0, 0, 0);
                }
                int ncol = n * 16 + m16;
                #pragma unroll
                for (int i2 = 0; i2 < 4; ++i2)
                    atomicAdd(&out_lds[st[i2] * OUTSTRIDE + ncol], sgt[i2] * acc[i2]);
            }
        }
    }
    __syncthreads();
    {
        float* outp = out + (((size_t)b * DOUT) * 64 + h) * 64;
        for (int idx = tid; idx < 64 * DOUT; idx += 256) {
            int w = idx & 63, o = idx >> 6;
            outp[(size_t)o * 4096 + w] = out_lds[w * OUTSTRIDE + o];
        }
    }
}

__global__ __launch_bounds__(256)
void prep_weights_only(const float* __restrict__ w_experts,
                       const float* __restrict__ w_shared,
                       unsigned short* __restrict__ wt)
{
    int e = blockIdx.x;
    const float* src = (e < 8) ? (w_experts + (size_t)e * DIN * DOUT) : w_shared;
    unsigned short* dst = wt + (size_t)e * DOUT * DIN;
    for (int idx = threadIdx.x; idx < DOUT * DIN; idx += 256) {
        int n = idx / DIN, k = idx - n * DIN;
        dst[idx] = f2bf(src[k * DOUT + n]);
    }
}

// =============================================================================
extern "C" void kernel_launch(void* const* d_in, const int* in_sizes, int n_in,
                              void* d_out, int out_size, void* d_ws, size_t ws_size,
                              hipStream_t stream)
{
    const float* x         = (const float*)d_in[0];
    const float* conv_w    = (const float*)d_in[1];
    const float* router_w  = (const float*)d_in[2];
    const float* w_experts = (const float*)d_in[3];
    const float* b_experts = (const float*)d_in[4];
    const float* w_shared  = (const float*)d_in[5];
    const float* b_shared  = (const float*)d_in[6];
    float* out = (float*)d_out;
    char* ws = (char*)d_ws;

    if (ws_size >= WS_TOTAL) {
        unsigned short* tokbuf  = (unsigned short*)(ws + WS_TOK);
        unsigned short* wt      = (unsigned short*)(ws + WS_WT);
        int*            cnt     = (int*)(ws + WS_CNT);
        int*            rowtok  = (int*)(ws + WS_RT);
        float*          rowgate = (float*)(ws + WS_RG);
        unsigned short* slab    = (unsigned short*)(ws + WS_SLAB);
        float*          lpart   = (float*)(ws + WS_SLAB);   // aliased, see layout

        k1a_conv<<<dim3(2048), dim3(256), 0, stream>>>(
            x, conv_w, router_w, tokbuf, lpart, cnt);
        k1b_route<<<dim3(256), dim3(256), 0, stream>>>(
            lpart, cnt, rowtok, rowgate, w_experts, w_shared, wt);
        k4_routed<<<dim3(2048), dim3(256), 0, stream>>>(
            tokbuf, wt, b_experts, cnt, rowtok, rowgate, slab);
        k3_shared<<<dim3(2048), dim3(256), 0, stream>>>(
            tokbuf, wt, slab, b_shared, out);
    } else {
        // fallback: round-3 fused path (needs only 442 KB ws)
        unsigned short* wt = (unsigned short*)ws;
        prep_weights_only<<<dim3(NMAT), dim3(256), 0, stream>>>(w_experts, w_shared, wt);
        moe_conv2d_mfma<<<dim3(1024), dim3(256), 0, stream>>>(
            x, conv_w, router_w, wt, b_experts, b_shared, out);
    }
}

// Round 14
// 168.558 us; speedup vs baseline: 1.3319x; 1.0593x over previous
//
#include <hip/hip_runtime.h>
#include <math.h>

// Problem constants
#define BB   16
#define CC   64
#define DIN  192     // C*K
#define DOUT 128
#define NEXP 8
#define NMAT 9       // 8 routed + 1 shared
#define NTOK 65536   // B*H*W
#define CAP  65568   // per-expert bucket capacity
#define SLABROWS 65552  // NTOK + 16 (dump rows for padding)

#define TOKSTRIDE 200   // LDS bf16 token row stride
#define HALFSTRIDE 104  // LDS bf16 stride for 96-f half rows
#define LOGSTRIDE 9
#define CSTRIDE 136     // k4 LDS C-tile stride (shorts)

typedef short bf16x8 __attribute__((ext_vector_type(8)));
typedef float f32x4  __attribute__((ext_vector_type(4)));

// ---- workspace layout (bytes) ----
#define WS_TOK   0u          // bf16[NTOK][192]            25165824
#define WS_WT    25165824u   // bf16[9][128][192]          442368
#define WS_CNT   25608192u   // int[16]                    64
#define WS_RT    25608256u   // int[8][CAP] token|slot<<20 2098176
#define WS_RG    27706432u   // float[8][CAP]              2098176
#define WS_SLAB  29804608u   // bf16[2 or 3][SLABROWS][128]
#define WS_TOTAL  63367232u  // 2-slab (middle tier)
#define WS_TOTAL3 80148544u  // 3-slab (top tier: shared expert in k4)
// lpart (fp32[2][NTOK][8] = 4 MB) aliases the START of WS_SLAB: written by
// k1a, read by k1b, then fully overwritten by k4 before k3 reads slab.
#define LPHALF 524288        // floats per channel-half

__device__ __forceinline__ unsigned short f2bf(float f) {
    union { float f; unsigned u; } v; v.f = f;
    unsigned u = v.u;
    u += 0x7fffu + ((u >> 16) & 1u);   // RNE (inputs finite)
    return (unsigned short)(u >> 16);
}
__device__ __forceinline__ float bf2f(unsigned short s) {
    union { unsigned u; float f; } v; v.u = ((unsigned)s) << 16;
    return v.f;
}

// ---------------- K1a: conv + router partials, LDS x-stage, pipelined ---------
// grid 2048 = (b,h) x chalf; x staged per 16-channel chunk via 3 float4
// coalesced loads/thread; chunk1 loads issued before chunk0 compute.
// NOTE (r12 lesson): tokbuf segments must stay 64B-aligned (half-split ok).
__global__ __launch_bounds__(256)
void k1a_conv(const float* __restrict__ x,
              const float* __restrict__ conv_w,
              const float* __restrict__ router_w,
              unsigned short* __restrict__ tokbuf,
              float* __restrict__ lpart,
              int* __restrict__ cnt)
{
    __shared__ __attribute__((aligned(16))) unsigned short tokbf[64 * HALFSTRIDE];
    __shared__ float logits[64 * LOGSTRIDE];
    __shared__ __attribute__((aligned(16))) float xs[2][16 * 192];  // 24.6 KB

    const int tid   = threadIdx.x;
    const int bid   = blockIdx.x;
    const int bh    = bid >> 1;
    const int chalf = bid & 1;
    const int b     = bh >> 6;
    const int h     = bh & 63;

    if (bid == 0 && tid < 16) cnt[tid] = 0;
    for (int idx = tid; idx < 64 * LOGSTRIDE; idx += 256) logits[idx] = 0.f;

    const int   h0  = (h > 0)  ? (h - 1) : 0;
    const int   h2  = (h < 63) ? (h + 1) : 63;
    const float mh0 = (h > 0)  ? 1.f : 0.f;
    const float mh2 = (h < 63) ? 1.f : 0.f;

    const int sc[3]  = { (0*256+tid)/48, (1*256+tid)/48, (2*256+tid)/48 };
    int srow[3], sseg[3];
    #pragma unroll
    for (int q = 0; q < 3; ++q) {
        int rem = (q * 256 + tid) % 48;
        srow[q] = rem >> 4; sseg[q] = rem & 15;
    }
    const float* xb = x + (size_t)b * CC * 4096;

    // ---- stage chunk 0 ----
    {
        float4 st[3];
        #pragma unroll
        for (int q = 0; q < 3; ++q) {
            int hh = (srow[q] == 0) ? h0 : ((srow[q] == 1) ? h : h2);
            st[q] = *(const float4*)(xb + ((size_t)(chalf * 32 + sc[q]) * 64 + hh) * 64
                                        + sseg[q] * 4);
        }
        #pragma unroll
        for (int q = 0; q < 3; ++q)
            *(float4*)&xs[0][sc[q] * 192 + srow[q] * 64 + sseg[q] * 4] = st[q];
    }
    __syncthreads();

    const int w  = tid & 63;
    const int cq = __builtin_amdgcn_readfirstlane(tid >> 6); // wave-uniform

    const int   wm  = (w == 0)  ? 0  : (w - 1);
    const int   wp  = (w == 63) ? 63 : (w + 1);
    const float mwm = (w == 0)  ? 0.f : 1.f;
    const float mwp = (w == 63) ? 0.f : 1.f;

    float lacc[8];
    #pragma unroll
    for (int e = 0; e < 8; ++e) lacc[e] = 0.f;

    // ---- issue chunk-1 loads (vmcnt wait lands after chunk-0 compute) ----
    float4 st1[3];
    #pragma unroll
    for (int q = 0; q < 3; ++q) {
        int hh = (srow[q] == 0) ? h0 : ((srow[q] == 1) ? h : h2);
        st1[q] = *(const float4*)(xb + ((size_t)(chalf * 32 + 16 + sc[q]) * 64 + hh) * 64
                                     + sseg[q] * 4);
    }

    // ---- compute both chunks ----
    #pragma unroll
    for (int ch = 0; ch < 2; ++ch) {
        const float* xsc = xs[ch];
        #pragma unroll
        for (int i = 0; i < 4; ++i) {
            int cc = cq * 4 + i;
            int cl = ch * 16 + cc;
            const float* r0 = xsc + cc * 192;
            const float* r1 = r0 + 64;
            const float* r2 = r0 + 128;
            float x00 = r0[wm], x01 = r0[w], x02 = r0[wp];
            float x10 = r1[wm], x11 = r1[w], x12 = r1[wp];
            float x20 = r2[wm], x21 = r2[w], x22 = r2[wp];
            x00 *= mh0 * mwm; x01 *= mh0; x02 *= mh0 * mwp;
            x10 *= mwm;                    x12 *= mwp;
            x20 *= mh2 * mwm; x21 *= mh2; x22 *= mh2 * mwp;

            #pragma unroll
            for (int j = 0; j < 3; ++j) {
                int fl = 3 * cl + j;
                int f  = chalf * 96 + fl;              // wave-uniform
                const float* w9 = conv_w + f * 9;      // scalar loads (L2-hot)
                float acc = x00 * w9[0] + x01 * w9[1] + x02 * w9[2]
                          + x10 * w9[3] + x11 * w9[4] + x12 * w9[5]
                          + x20 * w9[6] + x21 * w9[7] + x22 * w9[8];
                tokbf[w * HALFSTRIDE + fl] = f2bf(acc);
                const float* rwf = router_w + f * 8;   // scalar loads
                #pragma unroll
                for (int e = 0; e < 8; ++e) lacc[e] += acc * rwf[e];
            }
        }
        if (ch == 0) {
            #pragma unroll
            for (int q = 0; q < 3; ++q)
                *(float4*)&xs[1][sc[q] * 192 + srow[q] * 64 + sseg[q] * 4] = st1[q];
            __syncthreads();
        }
    }

    #pragma unroll
    for (int e = 0; e < 8; ++e)
        atomicAdd(&logits[w * LOGSTRIDE + e], lacc[e]);  // 4 threads/(w,e)
    __syncthreads();

    // partial logits -> global (coalesced)
    for (int idx = tid; idx < 512; idx += 256) {
        int wtok = idx >> 3, e = idx & 7;
        lpart[(size_t)chalf * LPHALF + ((size_t)bh * 64 + wtok) * 8 + e] =
            logits[wtok * LOGSTRIDE + e];
    }
    // tokens LDS -> global (bf16x8 chunks; 64 rows x 12 chunks; 192B aligned)
    for (int idx = tid; idx < 768; idx += 256) {
        int row = idx / 12, seg = idx - row * 12;
        *(bf16x8*)(tokbuf + (size_t)(bh * 64 + row) * 192 + chalf * 96 + seg * 8) =
            *(const bf16x8*)(tokbf + row * HALFSTRIDE + seg * 8);
    }
}

// ---------------- K1b: sum halves, top-2, parallel rank append + wt prep ------
__global__ __launch_bounds__(256)
void k1b_route(const float* __restrict__ lpart,
               int* __restrict__ cnt,
               int* __restrict__ rowtok, float* __restrict__ rowgate,
               const float* __restrict__ w_experts,
               const float* __restrict__ w_shared,
               unsigned short* __restrict__ wt)
{
    __shared__ int lcnt[8];
    __shared__ int lbase[8];

    const int tid = threadIdx.x;
    const int blk = blockIdx.x;
    const int t   = blk * 256 + tid;          // 256 blocks x 256 tokens

    if (tid < 8) lcnt[tid] = 0;
    __syncthreads();

    const float* p0 = lpart + (size_t)t * 8;
    const float* p1 = lpart + LPHALF + (size_t)t * 8;
    float l[8];
    #pragma unroll
    for (int e = 0; e < 8; ++e) l[e] = p0[e] + p1[e];

    // fp32 exact top-2; strict > keeps lowest index on ties (lax.top_k)
    int e0 = 0; float l0 = l[0];
    #pragma unroll
    for (int e = 1; e < 8; ++e) if (l[e] > l0) { l0 = l[e]; e0 = e; }
    int e1 = -1; float l1 = -INFINITY;
    #pragma unroll
    for (int e = 0; e < 8; ++e) {
        if (e == e0) continue;
        if (l[e] > l1) { l1 = l[e]; e1 = e; }
    }
    float g0 = 1.f / (1.f + expf(l1 - l0));   // softmax Z cancels in renorm
    float g1 = 1.f - g0;

    int r0 = atomicAdd(&lcnt[e0], 1);
    int r1 = atomicAdd(&lcnt[e1], 1);
    __syncthreads();
    if (tid < 8) lbase[tid] = atomicAdd(&cnt[tid], lcnt[tid]);
    __syncthreads();

    int p0i = e0 * CAP + lbase[e0] + r0;
    int p1i = e1 * CAP + lbase[e1] + r1;
    rowtok[p0i]  = t;
    rowgate[p0i] = g0;
    rowtok[p1i]  = t | (1 << 20);
    rowgate[p1i] = g1;

    // weight transpose slice: 864 elems/block of wt[e][n][k] = src[e][k][n]
    {
        int base = blk * 864;
        for (int q = 0; q < 4; ++q) {
            int idx = base + q * 256 + tid;
            if (idx < 221184 && (q * 256 + tid) < 864) {
                int e = idx / 24576, rem = idx - e * 24576;
                int n = rem / DIN,  k  = rem - n * DIN;
                const float* src = (e < 8) ? (w_experts + (size_t)e * DIN * DOUT)
                                           : w_shared;
                wt[idx] = f2bf(src[k * DOUT + n]);
            }
        }
    }
}

// ---------------- K4_all: routed (+ optionally shared) GEMM -> slot slabs -----
// blocks <2048: expert e=bid>>8, jb=bid&255, step 256 (bucketed rows).
// blocks >=2048 (top tier only): e=8 dense shared, jb=bid-2048, step 1024,
// slot-2 slab, gate 1, bias b_shared. Register-bounced A pipeline throughout.
__global__ __launch_bounds__(256)
void k4_all(const unsigned short* __restrict__ tokbuf,
            const unsigned short* __restrict__ wt,
            const float* __restrict__ b_experts,
            const float* __restrict__ b_shared,
            const int* __restrict__ cnt,
            const int* __restrict__ rowtok, const float* __restrict__ rowgate,
            unsigned short* __restrict__ slab)
{
    __shared__ __attribute__((aligned(16))) unsigned short atile[2][16 * TOKSTRIDE];
    __shared__ __attribute__((aligned(16))) unsigned short ctile[2][16 * CSTRIDE];
    __shared__ int   stok[2][16];
    __shared__ float sgate[2][16];

    const int tid  = threadIdx.x;
    int e, jb, jstep;
    if (blockIdx.x < 2048) { e = blockIdx.x >> 8; jb = blockIdx.x & 255; jstep = 256; }
    else                   { e = 8; jb = blockIdx.x - 2048; jstep = 1024; }
    const bool dense = (e == 8);

    const int wave = tid >> 6;
    const int lane = tid & 63;
    const int m16  = lane & 15, quad = lane >> 4;
    const int o0   = (wave * 2 + 0) * 16 + m16;
    const int o1   = (wave * 2 + 1) * 16 + m16;

    const unsigned short* wb = wt + (size_t)e * DOUT * DIN;
    bf16x8 bfr0[6], bfr1[6];
    #pragma unroll
    for (int ks = 0; ks < 6; ++ks) {
        bfr0[ks] = *(const bf16x8*)(wb + (size_t)o0 * DIN + ks * 32 + quad * 8);
        bfr1[ks] = *(const bf16x8*)(wb + (size_t)o1 * DIN + ks * 32 + quad * 8);
    }
    const float be0 = dense ? b_shared[o0] : b_experts[e * DOUT + o0];
    const float be1 = dense ? b_shared[o1] : b_experts[e * DOUT + o1];

    const int cnt_e  = dense ? NTOK : cnt[e];
    const int ntiles = (cnt_e + 15) >> 4;
    const int*   rt = rowtok  + e * CAP;
    const float* rg = rowgate + e * CAP;

    // staging map: idx = tid (+256): row=idx/24, seg=idx%24
    const int r0i = tid / 24,         s0i = tid - r0i * 24;
    const int r1i = (tid + 256) / 24, s1i = (tid + 256) - r1i * 24;
    const bool has1 = (tid + 256) < 384;

    #define FETCH_RAW(r) (dense ? ((r) | (2 << 20)) : (((r) < cnt_e) ? rt[r] : NTOK))
    #define FETCH_G(r)   (dense ? 1.f : (((r) < cnt_e) ? rg[r] : 0.f))

    // ---- prologue: stage tile jb into buf 0 ----
    if (jb < ntiles) {
        int base = jb * 16;
        if (tid < 16) {
            stok[0][tid]  = FETCH_RAW(base + tid);
            sgate[0][tid] = FETCH_G(base + tid);
        }
        {
            int rawa = FETCH_RAW(base + r0i);
            *(bf16x8*)&atile[0][r0i * TOKSTRIDE + s0i * 8] =
                *(const bf16x8*)(tokbuf + (size_t)(rawa & 0x1FFFF) * 192 + s0i * 8);
            if (has1) {
                int rawb = FETCH_RAW(base + r1i);
                *(bf16x8*)&atile[0][r1i * TOKSTRIDE + s1i * 8] =
                    *(const bf16x8*)(tokbuf + (size_t)(rawb & 0x1FFFF) * 192 + s1i * 8);
            }
        }
    }
    __syncthreads();

    int buf = 0;
    for (int j = jb; j < ntiles; j += jstep, buf ^= 1) {
        const int jn = j + jstep;
        const bool more = (jn < ntiles);

        // ---- issue next tile's global loads into registers (no use yet) ----
        bf16x8 nx0 = {0,0,0,0,0,0,0,0}, nx1 = {0,0,0,0,0,0,0,0};
        int nmt = NTOK; float nmg = 0.f;
        if (more) {
            int base = jn * 16;
            if (tid < 16) { nmt = FETCH_RAW(base + tid); nmg = FETCH_G(base + tid); }
            int rawa = FETCH_RAW(base + r0i);
            nx0 = *(const bf16x8*)(tokbuf + (size_t)(rawa & 0x1FFFF) * 192 + s0i * 8);
            if (has1) {
                int rawb = FETCH_RAW(base + r1i);
                nx1 = *(const bf16x8*)(tokbuf + (size_t)(rawb & 0x1FFFF) * 192 + s1i * 8);
            }
        }

        // ---- compute current tile ----
        bf16x8 a[6];
        #pragma unroll
        for (int ks = 0; ks < 6; ++ks)
            a[ks] = *(const bf16x8*)&atile[buf][m16 * TOKSTRIDE + ks * 32 + quad * 8];

        f32x4 acc0 = {0.f, 0.f, 0.f, 0.f};
        f32x4 acc1 = {0.f, 0.f, 0.f, 0.f};
        #pragma unroll
        for (int ks = 0; ks < 6; ++ks) {
            acc0 = __builtin_amdgcn_mfma_f32_16x16x32_bf16(a[ks], bfr0[ks], acc0, 0, 0, 0);
            acc1 = __builtin_amdgcn_mfma_f32_16x16x32_bf16(a[ks], bfr1[ks], acc1, 0, 0, 0);
        }

        #pragma unroll
        for (int i = 0; i < 4; ++i) {
            int   row = quad * 4 + i;
            float g   = sgate[buf][row];
            ctile[buf][row * CSTRIDE + o0] = f2bf(g * (acc0[i] + be0));
            ctile[buf][row * CSTRIDE + o1] = f2bf(g * (acc1[i] + be1));
        }

        // ---- publish next tile, barrier, wide 16B store ----
        if (more) {
            if (tid < 16) { stok[buf ^ 1][tid] = nmt; sgate[buf ^ 1][tid] = nmg; }
            *(bf16x8*)&atile[buf ^ 1][r0i * TOKSTRIDE + s0i * 8] = nx0;
            if (has1) *(bf16x8*)&atile[buf ^ 1][r1i * TOKSTRIDE + s1i * 8] = nx1;
        }
        __syncthreads();

        {
            int row = tid >> 4, chk = tid & 15;
            int raw = stok[buf][row];
            int t    = raw & 0x1FFFF;
            int slot = raw >> 20;
            *(bf16x8*)(slab + (size_t)slot * SLABROWS * DOUT
                            + (size_t)t * DOUT + chk * 8) =
                *(const bf16x8*)&ctile[buf][row * CSTRIDE + chk * 8];
        }
    }
    #undef FETCH_RAW
    #undef FETCH_G
}

// ---------------- K3_combine (top tier): out = slab0+slab1+slab2 --------------
// Pure streaming: no MFMA, no tokbuf/wt reads, one LDS transpose for the
// coalesced [B,O,H,W] store.
__global__ __launch_bounds__(256)
void k3_combine(const unsigned short* __restrict__ slab,
                float* __restrict__ out)
{
    __shared__ float out_lds[32 * 129];

    const int tid = threadIdx.x;
    const int bid = blockIdx.x;
    const int bh  = bid >> 1;
    const int wh  = bid & 1;
    const int b   = bh >> 6;
    const int h   = bh & 63;
    const int t0  = bh * 64 + wh * 32;

    const unsigned short* s0 = slab;
    const unsigned short* s1 = slab + (size_t)SLABROWS * DOUT;
    const unsigned short* s2 = slab + (size_t)2 * SLABROWS * DOUT;

    #pragma unroll
    for (int it = 0; it < 2; ++it) {
        int idx = it * 256 + tid;          // 512 = 32 tokens x 16 chunks
        int tl = idx >> 4, chk = idx & 15;
        size_t gt = (size_t)t0 + tl;
        bf16x8 v0 = *(const bf16x8*)(s0 + gt * DOUT + chk * 8);
        bf16x8 v1 = *(const bf16x8*)(s1 + gt * DOUT + chk * 8);
        bf16x8 v2 = *(const bf16x8*)(s2 + gt * DOUT + chk * 8);
        float* dst = &out_lds[tl * 129 + chk * 8];
        #pragma unroll
        for (int q = 0; q < 8; ++q)
            dst[q] = bf2f((unsigned short)v0[q]) + bf2f((unsigned short)v1[q])
                   + bf2f((unsigned short)v2[q]);
    }
    __syncthreads();

    float* outp = out + ((size_t)b * DOUT) * 4096 + h * 64 + wh * 32;
    for (int idx = tid; idx < 32 * DOUT; idx += 256) {
        int wloc = idx & 31, o = idx >> 5;
        outp[(size_t)o * 4096 + wloc] = out_lds[wloc * 129 + o];
    }
}

// ---------------- K3_shared (middle tier): shared GEMM + 2-slab combine -------
__global__ __launch_bounds__(256)
void k3_shared(const unsigned short* __restrict__ tokbuf,
               const unsigned short* __restrict__ wt,
               const unsigned short* __restrict__ slab,
               const float* __restrict__ b_shared,
               float* __restrict__ out)
{
    __shared__ float out_lds[32 * 129];       // 16.5 KB

    const int tid  = threadIdx.x;
    const int bid  = blockIdx.x;
    const int bh   = bid >> 1;
    const int wh   = bid & 1;
    const int b    = bh >> 6;
    const int h    = bh & 63;
    const int wave = tid >> 6, lane = tid & 63;
    const int mt   = wave >> 1, nh = wave & 1;
    const int m16  = lane & 15, quad = lane >> 4;
    const int t0   = bh * 64 + wh * 32;

    bf16x8 pv0[2], pv1[2];
    {
        const unsigned short* s0 = slab;
        const unsigned short* s1 = slab + (size_t)SLABROWS * DOUT;
        #pragma unroll
        for (int it = 0; it < 2; ++it) {
            int idx = it * 256 + tid;
            int tl = idx >> 4, chk = idx & 15;
            size_t gt = (size_t)t0 + tl;
            pv0[it] = *(const bf16x8*)(s0 + gt * DOUT + chk * 8);
            pv1[it] = *(const bf16x8*)(s1 + gt * DOUT + chk * 8);
        }
    }

    const unsigned short* ap =
        tokbuf + (size_t)(t0 + mt * 16 + m16) * 192 + quad * 8;
    bf16x8 a[6];
    #pragma unroll
    for (int ks = 0; ks < 6; ++ks) a[ks] = *(const bf16x8*)(ap + ks * 32);

    const unsigned short* wsh = wt + (size_t)8 * DOUT * DIN;

    bf16x8 bcur[6], bnxt[6];
    {
        int o = (nh * 4 + 0) * 16 + m16;
        const unsigned short* bp = wsh + (size_t)o * DIN + quad * 8;
        #pragma unroll
        for (int ks = 0; ks < 6; ++ks) bcur[ks] = *(const bf16x8*)(bp + ks * 32);
    }
    #pragma unroll
    for (int nb2 = 0; nb2 < 4; ++nb2) {
        if (nb2 < 3) {
            int on = (nh * 4 + nb2 + 1) * 16 + m16;
            const unsigned short* bp = wsh + (size_t)on * DIN + quad * 8;
            #pragma unroll
            for (int ks = 0; ks < 6; ++ks) bnxt[ks] = *(const bf16x8*)(bp + ks * 32);
        }
        int o = (nh * 4 + nb2) * 16 + m16;
        f32x4 acc = {0.f, 0.f, 0.f, 0.f};
        #pragma unroll
        for (int ks = 0; ks < 6; ++ks)
            acc = __builtin_amdgcn_mfma_f32_16x16x32_bf16(a[ks], bcur[ks], acc, 0, 0, 0);
        float bs = b_shared[o];
        #pragma unroll
        for (int i = 0; i < 4; ++i) {
            int tloc = mt * 16 + quad * 4 + i;
            out_lds[tloc * 129 + o] = acc[i] + bs;
        }
        #pragma unroll
        for (int ks = 0; ks < 6; ++ks) bcur[ks] = bnxt[ks];
    }
    __syncthreads();

    #pragma unroll
    for (int it = 0; it < 2; ++it) {
        int idx = it * 256 + tid;
        int tl = idx >> 4, chk = idx & 15;
        float* dst = &out_lds[tl * 129 + chk * 8];
        #pragma unroll
        for (int q = 0; q < 8; ++q)
            dst[q] += bf2f((unsigned short)pv0[it][q])
                    + bf2f((unsigned short)pv1[it][q]);
    }
    __syncthreads();

    float* outp = out + ((size_t)b * DOUT) * 4096 + h * 64 + wh * 32;
    for (int idx = tid; idx < 32 * DOUT; idx += 256) {
        int wloc = idx & 31, o = idx >> 5;
        outp[(size_t)o * 4096 + wloc] = out_lds[wloc * 129 + o];
    }
}

// ================== fallback (round-3 fused path, needs only 442 KB ws) ======
#define OUTSTRIDE 129
#define MAXROWS 320
#define MAXTILES 20

__global__ __launch_bounds__(256)
void moe_conv2d_mfma(const float* __restrict__ x,
                     const float* __restrict__ conv_w,
                     const float* __restrict__ router_w,
                     const unsigned short* __restrict__ wt,
                     const float* __restrict__ b_experts,
                     const float* __restrict__ b_shared,
                     float* __restrict__ out)
{
    __shared__ __attribute__((aligned(16))) unsigned short tokbf[64 * TOKSTRIDE];
    __shared__ float out_lds[64 * OUTSTRIDE];
    __shared__ float rw[DIN * NEXP];
    __shared__ float logits[64 * LOGSTRIDE];
    __shared__ float sg0[64], sg1[64];
    __shared__ int   se0[64], se1[64];
    __shared__ int   rowtok[MAXROWS];
    __shared__ float rowgate[MAXROWS];
    __shared__ int   cbuf[NMAT];
    __shared__ int   tilexp[MAXTILES], tilebase[MAXTILES];
    __shared__ int   ntiles_s;

    const int tid = threadIdx.x;
    const int bh  = blockIdx.x;
    const int b   = bh >> 6;
    const int h   = bh & 63;

    for (int idx = tid; idx < DIN * NEXP; idx += 256) rw[idx] = router_w[idx];
    for (int idx = tid; idx < 64 * LOGSTRIDE; idx += 256) logits[idx] = 0.f;
    __syncthreads();
    {
        const int w  = tid & 63;
        const int fq = tid >> 6;
        float lacc[8];
        #pragma unroll
        for (int e = 0; e < 8; ++e) lacc[e] = 0.f;
        for (int i = 0; i < 48; ++i) {
            int f = i * 4 + fq;
            int c = f / 3;
            const float* wp    = conv_w + f * 9;
            const float* xbase = x + ((size_t)(b * 64 + c) * 64) * 64;
            float acc = 0.f;
            #pragma unroll
            for (int kh = 0; kh < 3; ++kh) {
                int hh = h + kh - 1;
                if (hh < 0 || hh > 63) continue;
                const float* xrow = xbase + hh * 64;
                #pragma unroll
                for (int kw = 0; kw < 3; ++kw) {
                    int ww = w + kw - 1;
                    if (ww < 0 || ww > 63) continue;
                    acc += xrow[ww] * wp[kh * 3 + kw];
                }
            }
            tokbf[w * TOKSTRIDE + f] = f2bf(acc);
            const float* rwf = rw + f * 8;
            #pragma unroll
            for (int e = 0; e < 8; ++e) lacc[e] += acc * rwf[e];
        }
        #pragma unroll
        for (int e = 0; e < 8; ++e)
            atomicAdd(&logits[w * LOGSTRIDE + e], lacc[e]);
    }
    __syncthreads();
    if (tid < 64) {
        int w = tid;
        float l[8];
        #pragma unroll
        for (int e = 0; e < 8; ++e) l[e] = logits[w * LOGSTRIDE + e];
        int e0 = 0; float l0 = l[0];
        #pragma unroll
        for (int e = 1; e < 8; ++e) if (l[e] > l0) { l0 = l[e]; e0 = e; }
        int e1 = -1; float l1 = -INFINITY;
        #pragma unroll
        for (int e = 0; e < 8; ++e) {
            if (e == e0) continue;
            if (l[e] > l1) { l1 = l[e]; e1 = e; }
        }
        float g0 = 1.f / (1.f + expf(l1 - l0));
        sg0[w] = g0; sg1[w] = 1.f - g0;
        se0[w] = e0; se1[w] = e1;
    }
    __syncthreads();
    for (int idx = tid; idx < 64 * DOUT; idx += 256) {
        int t = idx >> 7, o = idx & 127;
        out_lds[t * OUTSTRIDE + o] = b_shared[o]
            + sg0[t] * b_experts[se0[t] * DOUT + o]
            + sg1[t] * b_experts[se1[t] * DOUT + o];
    }
    if (tid < 8) {
        int c = 0;
        for (int t = 0; t < 64; ++t) c += (se0[t] == tid) + (se1[t] == tid);
        cbuf[tid] = c;
    } else if (tid == 8) cbuf[8] = 64;
    __syncthreads();
    if (tid < NMAT) {
        int e = tid;
        int start = 0, tb = 0;
        for (int e2 = 0; e2 < e; ++e2) {
            int ce = cbuf[e2];
            int tl = (ce + 15) >> 4;
            start += tl << 4; tb += tl;
        }
        int ce = cbuf[e];
        int tl = (ce + 15) >> 4;
        for (int j = 0; j < tl; ++j) { tilexp[tb + j] = e; tilebase[tb + j] = start + (j << 4); }
        if (e == 8) ntiles_s = tb + tl;
        int j = 0;
        if (e < 8) {
            for (int t = 0; t < 64; ++t) {
                if (se0[t] == e) { rowtok[start + j] = t; rowgate[start + j] = sg0[t]; ++j; }
                if (se1[t] == e) { rowtok[start + j] = t; rowgate[start + j] = sg1[t]; ++j; }
            }
        } else {
            for (int t = 0; t < 64; ++t) { rowtok[start + j] = t; rowgate[start + j] = 1.f; ++j; }
        }
        for (; j < (tl << 4); ++j) { rowtok[start + j] = 0; rowgate[start + j] = 0.f; }
    }
    __syncthreads();
    {
        const int wave = tid >> 6;
        const int lane = tid & 63;
        const int m16  = lane & 15;
        const int quad = lane >> 4;
        const int nt   = ntiles_s;
        for (int ti = wave; ti < nt; ti += 4) {
            int e    = tilexp[ti];
            int base = tilebase[ti];
            int tA = rowtok[base + m16];
            bf16x8 a[6];
            #pragma unroll
            for (int ks = 0; ks < 6; ++ks)
                a[ks] = *(const bf16x8*)(tokbf + tA * TOKSTRIDE + ks * 32 + quad * 8);
            int st[4]; float sgt[4];
            #pragma unroll
            for (int i2 = 0; i2 < 4; ++i2) {
                int r = base + quad * 4 + i2;
                st[i2] = rowtok[r]; sgt[i2] = rowgate[r];
            }
            const unsigned short* we = wt + (size_t)e * DOUT * DIN;
            for (int n = 0; n < 8; ++n) {
                const unsigned short* wp = we + (size_t)(n * 16 + m16) * DIN + quad * 8;
                f32x4 acc = {0.f, 0.f, 0.f, 0.f};
                #pragma unroll
                for (int ks = 0; ks < 6; ++ks) {
                    bf16x8 bfr2 = *(const bf16x8*)(wp + ks * 32);
                    acc = __builtin_amdgcn_mfma_f32_16x16x32_bf16(a[ks], bfr2, acc, 0, 0, 0);
                }
                int ncol = n * 16 + m16;
                #pragma unroll
                for (int i2 = 0; i2 < 4; ++i2)
                    atomicAdd(&out_lds[st[i2] * OUTSTRIDE + ncol], sgt[i2] * acc[i2]);
            }
        }
    }
    __syncthreads();
    {
        float* outp = out + (((size_t)b * DOUT) * 64 + h) * 64;
        for (int idx = tid; idx < 64 * DOUT; idx += 256) {
            int w = idx & 63, o = idx >> 6;
            outp[(size_t)o * 4096 + w] = out_lds[w * OUTSTRIDE + o];
        }
    }
}

__global__ __launch_bounds__(256)
void prep_weights_only(const float* __restrict__ w_experts,
                       const float* __restrict__ w_shared,
                       unsigned short* __restrict__ wt)
{
    int e = blockIdx.x;
    const float* src = (e < 8) ? (w_experts + (size_t)e * DIN * DOUT) : w_shared;
    unsigned short* dst = wt + (size_t)e * DOUT * DIN;
    for (int idx = threadIdx.x; idx < DOUT * DIN; idx += 256) {
        int n = idx / DIN, k = idx - n * DIN;
        dst[idx] = f2bf(src[k * DOUT + n]);
    }
}

// =============================================================================
extern "C" void kernel_launch(void* const* d_in, const int* in_sizes, int n_in,
                              void* d_out, int out_size, void* d_ws, size_t ws_size,
                              hipStream_t stream)
{
    const float* x         = (const float*)d_in[0];
    const float* conv_w    = (const float*)d_in[1];
    const float* router_w  = (const float*)d_in[2];
    const float* w_experts = (const float*)d_in[3];
    const float* b_experts = (const float*)d_in[4];
    const float* w_shared  = (const float*)d_in[5];
    const float* b_shared  = (const float*)d_in[6];
    float* out = (float*)d_out;
    char* ws = (char*)d_ws;

    if (ws_size >= WS_TOTAL) {
        unsigned short* tokbuf  = (unsigned short*)(ws + WS_TOK);
        unsigned short* wt      = (unsigned short*)(ws + WS_WT);
        int*            cnt     = (int*)(ws + WS_CNT);
        int*            rowtok  = (int*)(ws + WS_RT);
        float*          rowgate = (float*)(ws + WS_RG);
        unsigned short* slab    = (unsigned short*)(ws + WS_SLAB);
        float*          lpart   = (float*)(ws + WS_SLAB);   // aliased, see layout

        k1a_conv<<<dim3(2048), dim3(256), 0, stream>>>(
            x, conv_w, router_w, tokbuf, lpart, cnt);
        k1b_route<<<dim3(256), dim3(256), 0, stream>>>(
            lpart, cnt, rowtok, rowgate, w_experts, w_shared, wt);
        if (ws_size >= WS_TOTAL3) {
            // top tier: shared expert = dense bucket in k4 (slot-2 slab),
            // k3 = pure streaming combine
            k4_all<<<dim3(3072), dim3(256), 0, stream>>>(
                tokbuf, wt, b_experts, b_shared, cnt, rowtok, rowgate, slab);
            k3_combine<<<dim3(2048), dim3(256), 0, stream>>>(slab, out);
        } else {
            // middle tier: 2-slab layout, shared GEMM inside k3
            k4_all<<<dim3(2048), dim3(256), 0, stream>>>(
                tokbuf, wt, b_experts, b_shared, cnt, rowtok, rowgate, slab);
            k3_shared<<<dim3(2048), dim3(256), 0, stream>>>(
                tokbuf, wt, slab, b_shared, out);
        }
    } else {
        // fallback: round-3 fused path (needs only 442 KB ws)
        unsigned short* wt = (unsigned short*)ws;
        prep_weights_only<<<dim3(NMAT), dim3(256), 0, stream>>>(w_experts, w_shared, wt);
        moe_conv2d_mfma<<<dim3(1024), dim3(256), 0, stream>>>(
            x, conv_w, router_w, wt, b_experts, b_shared, out);
    }
}